// Round 3
// baseline (155.408 us; speedup 1.0000x reference)
//
#include <hip/hip_runtime.h>
#include <math.h>

#define H 2048
#define E 64
#define RB 16         // rows per block
#define CB 512        // h-chunk staged in LDS
#define NCH (H / CB)  // 4 chunks
#define PITCHD 516    // f64 row pitch (rows offset 32B -> bank spread)

__global__ __launch_bounds__(256)
void router_kernel(const float* __restrict__ x,
                   const float* __restrict__ pds,
                   const float* __restrict__ Wm,
                   float* __restrict__ out)
{
    // yd [RB][PITCHD] f64 (66048 B); later aliased as partials [4][RB][E] f64 (32 KB)
    __shared__ __align__(16) double yd[RB * PITCHD];
    __shared__ float ssbuf[256];
    __shared__ double sfacd[RB];

    const int t    = threadIdx.x;
    const int wv_i = t >> 6;       // wave 0..3 (owns 128-h subrange of each chunk)
    const int lane = t & 63;
    const int g    = lane >> 4;    // row-group -> rows {g,4+g,8+g,12+g}
    const int eg   = lane & 15;
    const int e0   = eg << 2;      // 4 experts per lane in GEMV phase

    const int row0 = blockIdx.x * RB;
    const int srow = t >> 4;       // staging row 0..15
    const int sseg = t & 15;       // staging 4-float segment

    const float* xrow = x + (size_t)(row0 + srow) * H;

    double acc[4][4];              // [row rr][e], static indexing only
#pragma unroll
    for (int a = 0; a < 4; ++a)
#pragma unroll
        for (int b = 0; b < 4; ++b) acc[a][b] = 0.0;

    float sumsq = 0.0f;

    // prefetch chunk 0 (16 consecutive lanes -> 256B coalesced)
    float4 xv[8];
#pragma unroll
    for (int i = 0; i < 8; ++i) {
        const int hl = sseg * 4 + i * 64;
        xv[i] = *(const float4*)(xrow + hl);
    }

    for (int c = 0; c < NCH; ++c) {
        // ---- stage y = x*pds into LDS as EXACT f64 products; accumulate sum(x^2) ----
        const float* pbase = pds + c * CB;
#pragma unroll
        for (int i = 0; i < 8; ++i) {
            const int hl = sseg * 4 + i * 64;
            const float4 a4 = xv[i];
            const float4 p4 = *(const float4*)(pbase + hl);
            sumsq += a4.x * a4.x + a4.y * a4.y + a4.z * a4.z + a4.w * a4.w;
            double2 d0, d1;
            d0.x = (double)a4.x * (double)p4.x;
            d0.y = (double)a4.y * (double)p4.y;
            d1.x = (double)a4.z * (double)p4.z;
            d1.y = (double)a4.w * (double)p4.w;
            *(double2*)(&yd[srow * PITCHD + hl])     = d0;
            *(double2*)(&yd[srow * PITCHD + hl + 2]) = d1;
        }
        __syncthreads();

        // ---- issue next chunk's x loads; latency hides under the f64 GEMV ----
        if (c + 1 < NCH) {
            const int h0n = (c + 1) * CB;
#pragma unroll
            for (int i = 0; i < 8; ++i) {
                const int hl = sseg * 4 + i * 64;
                xv[i] = *(const float4*)(xrow + h0n + hl);
            }
        }

        // ---- f64 GEMV: each W quad converted once, reused across 4 rows ----
        const int hb = wv_i * 128;
        const float* wbase = Wm + (size_t)(c * CB) * E + e0;
        for (int s = 0; s < 32; ++s) {
            const int hh = hb + s * 4;
            const float4 w0 = *(const float4*)(wbase + (size_t)(hh + 0) * E);
            const float4 w1 = *(const float4*)(wbase + (size_t)(hh + 1) * E);
            const float4 w2 = *(const float4*)(wbase + (size_t)(hh + 2) * E);
            const float4 w3 = *(const float4*)(wbase + (size_t)(hh + 3) * E);
            const double w0x = (double)w0.x, w0y = (double)w0.y, w0z = (double)w0.z, w0w = (double)w0.w;
            const double w1x = (double)w1.x, w1y = (double)w1.y, w1z = (double)w1.z, w1w = (double)w1.w;
            const double w2x = (double)w2.x, w2y = (double)w2.y, w2z = (double)w2.z, w2w = (double)w2.w;
            const double w3x = (double)w3.x, w3y = (double)w3.y, w3z = (double)w3.z, w3w = (double)w3.w;
#pragma unroll
            for (int rr = 0; rr < 4; ++rr) {
                const double2 ya = *(const double2*)(&yd[(4 * rr + g) * PITCHD + hh]);
                const double2 yb = *(const double2*)(&yd[(4 * rr + g) * PITCHD + hh + 2]);
                acc[rr][0] = fma(yb.y, w3x, fma(yb.x, w2x, fma(ya.y, w1x, fma(ya.x, w0x, acc[rr][0]))));
                acc[rr][1] = fma(yb.y, w3y, fma(yb.x, w2y, fma(ya.y, w1y, fma(ya.x, w0y, acc[rr][1]))));
                acc[rr][2] = fma(yb.y, w3z, fma(yb.x, w2z, fma(ya.y, w1z, fma(ya.x, w0z, acc[rr][2]))));
                acc[rr][3] = fma(yb.y, w3w, fma(yb.x, w2w, fma(ya.y, w1w, fma(ya.x, w0w, acc[rr][3]))));
            }
        }
        __syncthreads();
    }

    // ---- RMS factor per row (common positive scale; computed in f64) ----
    ssbuf[t] = sumsq;
    __syncthreads();
    if (t < RB) {
        float tot = 0.0f;
#pragma unroll
        for (int i = 0; i < 16; ++i) tot += ssbuf[t * 16 + i];
        // rsqrt(mean + eps) * H^-0.5 ; per_dim_scale already folded into y
        sfacd[t] = (1.0 / sqrt((double)tot * (1.0 / (double)H) + 1e-6)) * 0.022097086912079608;
    }

    // ---- per-wave f64 partial logits (aliases yd; all GEMV reads done) ----
    double* part = yd;
#pragma unroll
    for (int rr = 0; rr < 4; ++rr) {
        const int r = 4 * rr + g;
        *(double2*)(&part[((wv_i * RB) + r) * E + e0])     = make_double2(acc[rr][0], acc[rr][1]);
        *(double2*)(&part[((wv_i * RB) + r) * E + e0 + 2]) = make_double2(acc[rr][2], acc[rr][3]);
    }
    __syncthreads();

    // ---- epilogue: wave wv_i owns rows 4*wv_i..+3; lane = expert.
    //      Mimic the numpy reference comparator: rank by f32-quantized softmax
    //      probs (not exact logits), stable lower-index tie-break. ----
#pragma unroll
    for (int rr = 0; rr < 4; ++rr) {
        const int r = wv_i * 4 + rr;
        const double Ld = part[(0 * RB + r) * E + lane] + part[(1 * RB + r) * E + lane]
                        + part[(2 * RB + r) * E + lane] + part[(3 * RB + r) * E + lane];
        const float L = (float)(Ld * sfacd[r]);   // single rounding to f32 logit

        // row max (exact, order-free)
        float m = L;
#pragma unroll
        for (int off = 32; off >= 1; off >>= 1)
            m = fmaxf(m, __shfl_xor(m, off));

        // e = exp(L - m), correctly-rounded f32 via f64 exp (monotone in L)
        const float tt = L - m;                    // IEEE f32 subtract, monotone
        const float e  = (float)exp((double)tt);

        // S: common divisor -> summation order is ranking-irrelevant
        float S = e;
#pragma unroll
        for (int off = 32; off >= 1; off >>= 1)
            S += __shfl_xor(S, off);

        const float p = e / S;                     // IEEE f32 divide (monotone in e)

        // top-1 on probs, smaller-index tie-break (stable argsort semantics)
        float v1 = p; int i1 = lane;
#pragma unroll
        for (int off = 32; off >= 1; off >>= 1) {
            const float ov = __shfl_xor(v1, off);
            const int   oi = __shfl_xor(i1, off);
            if (ov > v1 || (ov == v1 && oi < i1)) { v1 = ov; i1 = oi; }
        }
        // top-2
        float v2 = (lane == i1) ? -1.0f : p; int i2 = lane;
#pragma unroll
        for (int off = 32; off >= 1; off >>= 1) {
            const float ov = __shfl_xor(v2, off);
            const int   oi = __shfl_xor(i2, off);
            if (ov > v2 || (ov == v2 && oi < i2)) { v2 = ov; i2 = oi; }
        }

        // normalized weights from the quantized probs, like the reference
        const float denom = fmaxf(v1 + v2, 1e-9f);
        const float wA = v1 / denom;
        const float wB = v2 / denom;
        const float o  = (lane == i1) ? wA : ((lane == i2) ? wB : 0.0f);
        out[(size_t)(row0 + r) * E + lane] = o;
    }
}

extern "C" void kernel_launch(void* const* d_in, const int* in_sizes, int n_in,
                              void* d_out, int out_size, void* d_ws, size_t ws_size,
                              hipStream_t stream) {
    const float* x   = (const float*)d_in[0];
    const float* pds = (const float*)d_in[1];
    const float* Wm  = (const float*)d_in[2];
    float* out = (float*)d_out;

    const int T = in_sizes[0] / H;     // 16384
    const int grid = T / RB;           // 1024 blocks
    hipLaunchKernelGGL(router_kernel, dim3(grid), dim3(256), 0, stream,
                       x, pds, Wm, out);
}